// Round 1
// baseline (605.537 us; speedup 1.0000x reference)
//
#include <hip/hip_runtime.h>
#include <hip/hip_bf16.h>

#define NN      50000
#define EE      800000
#define ETOT    (EE + NN)        // + self loops
#define GG      64
#define HEADS   4
#define HID     25
#define DENSE   100
#define IN_DIM  128
#define OUT_DIM 2
#define NPC     5
#define NUM_PROT (OUT_DIM * NPC)
#define NCHUNK  ((NN + 255) / 256)

#define NEG_INF (-3.402823466e38f)

// ---------------- CSR build ----------------
__global__ void k_count(const int* __restrict__ ei, int* __restrict__ cnt, int* __restrict__ pos) {
    int e = blockIdx.x * blockDim.x + threadIdx.x;
    if (e >= ETOT) return;
    int dst = (e < EE) ? ei[EE + e] : (e - EE);
    pos[e] = atomicAdd(&cnt[dst], 1);
}

__global__ void k_scan1(const int* __restrict__ cnt, int* __restrict__ csum) {
    __shared__ int sh[256];
    int i = blockIdx.x * 256 + threadIdx.x;
    int v = (i < NN) ? cnt[i] : 0;
    sh[threadIdx.x] = v;
    __syncthreads();
    for (int s = 128; s > 0; s >>= 1) {
        if (threadIdx.x < s) sh[threadIdx.x] += sh[threadIdx.x + s];
        __syncthreads();
    }
    if (threadIdx.x == 0) csum[blockIdx.x] = sh[0];
}

__global__ void k_scan2(int* __restrict__ csum) {
    __shared__ int sh[256];
    int tid = threadIdx.x;
    int v = (tid < NCHUNK) ? csum[tid] : 0;
    sh[tid] = v;
    __syncthreads();
    for (int s = 1; s < 256; s <<= 1) {
        int t = (tid >= s) ? sh[tid - s] : 0;
        __syncthreads();
        sh[tid] += t;
        __syncthreads();
    }
    if (tid < NCHUNK) csum[tid] = sh[tid] - v;     // exclusive
    if (tid == NCHUNK) csum[NCHUNK] = sh[255];     // total
}

__global__ void k_scan3(const int* __restrict__ cnt, const int* __restrict__ csum, int* __restrict__ offs) {
    __shared__ int sh[256];
    int i = blockIdx.x * 256 + threadIdx.x;
    int v = (i < NN) ? cnt[i] : 0;
    sh[threadIdx.x] = v;
    __syncthreads();
    for (int s = 1; s < 256; s <<= 1) {
        int t = (threadIdx.x >= s) ? sh[threadIdx.x - s] : 0;
        __syncthreads();
        sh[threadIdx.x] += t;
        __syncthreads();
    }
    int excl = sh[threadIdx.x] - v + csum[blockIdx.x];
    if (i <= NN) offs[i] = excl;
}

__global__ void k_scatter(const int* __restrict__ ei, const int* __restrict__ offs,
                          const int* __restrict__ pos, int* __restrict__ csr) {
    int e = blockIdx.x * blockDim.x + threadIdx.x;
    if (e >= ETOT) return;
    int src, dst;
    if (e < EE) { src = ei[e]; dst = ei[EE + e]; }
    else        { src = dst = e - EE; }
    csr[offs[dst] + pos[e]] = src;
}

// ---------------- graph boundaries (batch is sorted) ----------------
__global__ void k_bounds(const int* __restrict__ batch, int* __restrict__ gstart) {
    int n = blockIdx.x * blockDim.x + threadIdx.x;
    if (n >= NN) return;
    int b = batch[n];
    if (n == 0) {
        for (int g = 0; g <= b; g++) gstart[g] = 0;
    } else {
        int pb = batch[n - 1];
        for (int g = pb + 1; g <= b; g++) gstart[g] = n;
    }
    if (n == NN - 1) {
        for (int g = b + 1; g <= GG; g++) gstart[g] = NN;
    }
}

// ---------------- GEMM: H = X @ W  ([N,DIN] x [DIN,100]) ----------------
template <int DIN>
__global__ __launch_bounds__(256) void k_gemm(const float* __restrict__ X,
                                              const float* __restrict__ W,
                                              float* __restrict__ H) {
    __shared__ float Ws[DIN * 104];   // pad rows 100 -> 104 (16B-aligned float4)
    __shared__ float Xs[8 * DIN];
    const int tid = threadIdx.x;

    for (int idx = tid; idx < DIN * 100; idx += 256) {
        int k = idx / 100, c = idx - k * 100;
        Ws[k * 104 + c] = W[idx];
    }

    const int node0 = blockIdx.x * 32;
    const int rl = tid >> 5;    // 0..7
    const int cg = tid & 31;    // 0..31 (25 active)

    for (int rb = 0; rb < 4; ++rb) {
        __syncthreads();
        int base = node0 + rb * 8;
        for (int idx = tid; idx < 8 * DIN; idx += 256) {
            int r = idx / DIN, k = idx - r * DIN;
            int row = base + r;
            Xs[idx] = (row < NN) ? X[(size_t)row * DIN + k] : 0.f;
        }
        __syncthreads();
        if (cg < 25) {
            float a0 = 0, a1 = 0, a2 = 0, a3 = 0;
            const float* xrow = &Xs[rl * DIN];
            #pragma unroll 8
            for (int k = 0; k < DIN; k++) {
                float xv = xrow[k];
                float4 w = *reinterpret_cast<const float4*>(&Ws[k * 104 + cg * 4]);
                a0 += xv * w.x; a1 += xv * w.y; a2 += xv * w.z; a3 += xv * w.w;
            }
            int row = base + rl;
            if (row < NN) {
                float* hp = &H[(size_t)row * 100 + cg * 4];
                float2 v0 = {a0, a1}, v1 = {a2, a3};
                *reinterpret_cast<float2*>(hp) = v0;
                *reinterpret_cast<float2*>(hp + 2) = v1;
            }
        }
    }
}

// ---------------- per-node attention logits: es/ed ----------------
__global__ void k_esed(const float* __restrict__ H, const float* __restrict__ AS,
                       const float* __restrict__ AD, float* __restrict__ es, float* __restrict__ ed) {
    int t = blockIdx.x * blockDim.x + threadIdx.x;
    if (t >= NN * HEADS) return;
    int n = t >> 2, hd = t & 3;
    const float* hr = H + (size_t)n * 100 + hd * 25;
    const float* as = AS + hd * 25;
    const float* ad = AD + hd * 25;
    float s1 = 0.f, s2 = 0.f;
    #pragma unroll
    for (int d = 0; d < 25; d++) {
        float v = hr[d];
        s1 += v * as[d];
        s2 += v * ad[d];
    }
    es[t] = s1;
    ed[t] = s2;
}

// ---------------- edge aggregation (online softmax per node) ----------------
__global__ __launch_bounds__(128) void k_agg(const float* __restrict__ H, const float* __restrict__ es,
                                             const float* __restrict__ ed, const int* __restrict__ offs,
                                             const int* __restrict__ csr, const float* __restrict__ bias,
                                             float* __restrict__ out) {
    int n = blockIdx.x;
    int d = threadIdx.x;
    __shared__ float edn[4];
    if (d < 4) edn[d] = ed[n * 4 + d];
    __syncthreads();
    if (d >= 100) return;
    int hd = d / 25;
    float edh = edn[hd];
    int beg = offs[n], end = offs[n + 1];
    float m = NEG_INF, s = 0.f, acc = 0.f;
    for (int e = beg; e < end; ++e) {
        int si = csr[e];
        float a = es[si * 4 + hd] + edh;
        a = (a > 0.f) ? a : 0.2f * a;
        float xv = H[(size_t)si * 100 + d];
        float nm = fmaxf(m, a);
        float sc = __expf(m - nm);
        float p  = __expf(a - nm);
        s   = s * sc + p;
        acc = acc * sc + p * xv;
        m = nm;
    }
    float o = acc / (s + 1e-16f) + bias[d];
    out[(size_t)n * 100 + d] = (o > 0.f) ? o : 0.f;
}

// ---------------- global max pool (2-level) ----------------
__global__ void k_pool1(const float* __restrict__ NE, const int* __restrict__ gstart,
                        float* __restrict__ part) {
    int g = blockIdx.x >> 3, c = blockIdx.x & 7;
    int d = threadIdx.x;
    if (d >= 100) return;
    int s0 = gstart[g], s1 = gstart[g + 1];
    int len = s1 - s0;
    int n0 = s0 + (int)((long long)len * c / 8);
    int n1 = s0 + (int)((long long)len * (c + 1) / 8);
    float vm = NEG_INF;
    for (int n = n0; n < n1; n++) vm = fmaxf(vm, NE[(size_t)n * 100 + d]);
    part[(size_t)(g * 8 + c) * 100 + d] = vm;
}

__global__ void k_pool2(const float* __restrict__ part, float* __restrict__ GE) {
    int g = blockIdx.x;
    int d = threadIdx.x;
    if (d >= 100) return;
    float vm = NEG_INF;
    for (int c = 0; c < 8; c++) vm = fmaxf(vm, part[(size_t)(g * 8 + c) * 100 + d]);
    GE[(size_t)g * 100 + d] = vm;
}

// ---------------- prototype head ----------------
__global__ void k_head(const float* __restrict__ GE, const float* __restrict__ P,
                       const float* __restrict__ LW, float* __restrict__ logits,
                       float* __restrict__ probs, float* __restrict__ dist) {
    int g = blockIdx.x;
    __shared__ float ge[100];
    __shared__ float sims[NUM_PROT];
    __shared__ float lg[OUT_DIM];
    int t = threadIdx.x;
    if (t < 100) ge[t] = GE[(size_t)g * 100 + t];
    __syncthreads();
    if (t < NUM_PROT) {
        float dot = 0.f, pn = 0.f, gn = 0.f;
        for (int d = 0; d < 100; d++) {
            float pv = P[t * 100 + d];
            float gv = ge[d];
            dot += gv * pv;
            pn += pv * pv;
            gn += gv * gv;
        }
        float ds = gn - 2.f * dot + pn;
        dist[g * NUM_PROT + t] = ds;
        sims[t] = logf((ds + 1.f) / (ds + 1e-4f));
    }
    __syncthreads();
    if (t < OUT_DIM) {
        float l = 0.f;
        for (int p = 0; p < NUM_PROT; p++) l += sims[p] * LW[t * NUM_PROT + p];
        lg[t] = l;
        logits[g * OUT_DIM + t] = l;
    }
    __syncthreads();
    if (t == 0) {
        float mm = fmaxf(lg[0], lg[1]);
        float e0 = __expf(lg[0] - mm), e1 = __expf(lg[1] - mm);
        float inv = 1.f / (e0 + e1);
        probs[g * OUT_DIM + 0] = e0 * inv;
        probs[g * OUT_DIM + 1] = e1 * inv;
    }
}

extern "C" void kernel_launch(void* const* d_in, const int* in_sizes, int n_in,
                              void* d_out, int out_size, void* d_ws, size_t ws_size,
                              hipStream_t stream) {
    const float* x     = (const float*)d_in[0];
    const int*   ei    = (const int*)d_in[1];
    const int*   batch = (const int*)d_in[2];
    const float* Wm[3]  = {(const float*)d_in[3],  (const float*)d_in[7],  (const float*)d_in[11]};
    const float* ASm[3] = {(const float*)d_in[4],  (const float*)d_in[8],  (const float*)d_in[12]};
    const float* ADm[3] = {(const float*)d_in[5],  (const float*)d_in[9],  (const float*)d_in[13]};
    const float* Bm[3]  = {(const float*)d_in[6],  (const float*)d_in[10], (const float*)d_in[14]};
    const float* P  = (const float*)d_in[15];
    const float* LW = (const float*)d_in[16];

    float* out = (float*)d_out;
    float* logits  = out;                                   // [64,2]
    float* probs   = out + GG * OUT_DIM;                    // [64,2]
    float* nodeEmb = out + 2 * GG * OUT_DIM;                // [N,100]  (also ping buffer B)
    float* GE      = nodeEmb + (size_t)NN * DENSE;          // [64,100]
    float* disto   = GE + GG * DENSE;                       // [64,10]

    // workspace carve-up
    char* w = (char*)d_ws;
    size_t off = 0;
    auto carve = [&](size_t bytes) -> void* {
        void* p = w + off;
        off += (bytes + 15) & ~(size_t)15;
        return p;
    };
    float* hA   = (float*)carve((size_t)NN * DENSE * 4);     // buffer A (gemm out / agg in)
    float* es   = (float*)carve((size_t)NN * HEADS * 4);
    float* ed   = (float*)carve((size_t)NN * HEADS * 4);
    int* cnt    = (int*)carve((size_t)NN * 4);
    int* offs   = (int*)carve((size_t)(NN + 1) * 4);
    int* pos    = (int*)carve((size_t)ETOT * 4);
    int* csr    = (int*)carve((size_t)ETOT * 4);
    int* csum   = (int*)carve((size_t)(NCHUNK + 1) * 4);
    int* gstart = (int*)carve((size_t)(GG + 1) * 4);
    float* part = (float*)carve((size_t)GG * 8 * DENSE * 4);
    (void)ws_size; (void)in_sizes; (void)n_in; (void)out_size;

    // ---- CSR build (once, reused for all 3 layers) ----
    hipMemsetAsync(cnt, 0, (size_t)NN * 4, stream);
    k_count<<<(ETOT + 255) / 256, 256, 0, stream>>>(ei, cnt, pos);
    k_scan1<<<NCHUNK, 256, 0, stream>>>(cnt, csum);
    k_scan2<<<1, 256, 0, stream>>>(csum);
    k_scan3<<<NCHUNK, 256, 0, stream>>>(cnt, csum, offs);
    k_scatter<<<(ETOT + 255) / 256, 256, 0, stream>>>(ei, offs, pos, csr);
    k_bounds<<<(NN + 255) / 256, 256, 0, stream>>>(batch, gstart);

    const int gemmGrid = (NN + 31) / 32;
    const int esedGrid = (NN * HEADS + 255) / 256;

    // ---- layer 0: x -> A -> B(nodeEmb region as scratch) ----
    k_gemm<IN_DIM><<<gemmGrid, 256, 0, stream>>>(x, Wm[0], hA);
    k_esed<<<esedGrid, 256, 0, stream>>>(hA, ASm[0], ADm[0], es, ed);
    k_agg<<<NN, 128, 0, stream>>>(hA, es, ed, offs, csr, Bm[0], nodeEmb);

    // ---- layer 1: B -> A -> B ----
    k_gemm<DENSE><<<gemmGrid, 256, 0, stream>>>(nodeEmb, Wm[1], hA);
    k_esed<<<esedGrid, 256, 0, stream>>>(hA, ASm[1], ADm[1], es, ed);
    k_agg<<<NN, 128, 0, stream>>>(hA, es, ed, offs, csr, Bm[1], nodeEmb);

    // ---- layer 2: B -> A -> B (final node_emb) ----
    k_gemm<DENSE><<<gemmGrid, 256, 0, stream>>>(nodeEmb, Wm[2], hA);
    k_esed<<<esedGrid, 256, 0, stream>>>(hA, ASm[2], ADm[2], es, ed);
    k_agg<<<NN, 128, 0, stream>>>(hA, es, ed, offs, csr, Bm[2], nodeEmb);

    // ---- pooling ----
    k_pool1<<<GG * 8, 128, 0, stream>>>(nodeEmb, gstart, part);
    k_pool2<<<GG, 128, 0, stream>>>(part, GE);

    // ---- prototype head ----
    k_head<<<GG, 128, 0, stream>>>(GE, P, LW, logits, probs, disto);
}

// Round 2
// 493.277 us; speedup vs baseline: 1.2276x; 1.2276x over previous
//
#include <hip/hip_runtime.h>
#include <hip/hip_bf16.h>

#define NN      50000
#define EE      800000
#define ETOT    (EE + NN)        // + self loops
#define GG      64
#define HEADS   4
#define HID     25
#define DENSE   100
#define IN_DIM  128
#define OUT_DIM 2
#define NPC     5
#define NUM_PROT (OUT_DIM * NPC)
#define NCHUNK  ((NN + 255) / 256)

#define NEG_INF (-3.402823466e38f)

// ---------------- CSR build ----------------
__global__ void k_count(const int* __restrict__ ei, int* __restrict__ cnt, int* __restrict__ pos) {
    int e = blockIdx.x * blockDim.x + threadIdx.x;
    if (e >= ETOT) return;
    int dst = (e < EE) ? ei[EE + e] : (e - EE);
    pos[e] = atomicAdd(&cnt[dst], 1);
}

__global__ void k_scan1(const int* __restrict__ cnt, int* __restrict__ csum) {
    __shared__ int sh[256];
    int i = blockIdx.x * 256 + threadIdx.x;
    int v = (i < NN) ? cnt[i] : 0;
    sh[threadIdx.x] = v;
    __syncthreads();
    for (int s = 128; s > 0; s >>= 1) {
        if (threadIdx.x < s) sh[threadIdx.x] += sh[threadIdx.x + s];
        __syncthreads();
    }
    if (threadIdx.x == 0) csum[blockIdx.x] = sh[0];
}

__global__ void k_scan2(int* __restrict__ csum) {
    __shared__ int sh[256];
    int tid = threadIdx.x;
    int v = (tid < NCHUNK) ? csum[tid] : 0;
    sh[tid] = v;
    __syncthreads();
    for (int s = 1; s < 256; s <<= 1) {
        int t = (tid >= s) ? sh[tid - s] : 0;
        __syncthreads();
        sh[tid] += t;
        __syncthreads();
    }
    if (tid < NCHUNK) csum[tid] = sh[tid] - v;     // exclusive
    if (tid == NCHUNK) csum[NCHUNK] = sh[255];     // total
}

__global__ void k_scan3(const int* __restrict__ cnt, const int* __restrict__ csum, int* __restrict__ offs) {
    __shared__ int sh[256];
    int i = blockIdx.x * 256 + threadIdx.x;
    int v = (i < NN) ? cnt[i] : 0;
    sh[threadIdx.x] = v;
    __syncthreads();
    for (int s = 1; s < 256; s <<= 1) {
        int t = (threadIdx.x >= s) ? sh[threadIdx.x - s] : 0;
        __syncthreads();
        sh[threadIdx.x] += t;
        __syncthreads();
    }
    int excl = sh[threadIdx.x] - v + csum[blockIdx.x];
    if (i <= NN) offs[i] = excl;
}

__global__ void k_scatter(const int* __restrict__ ei, const int* __restrict__ offs,
                          const int* __restrict__ pos, int* __restrict__ csr) {
    int e = blockIdx.x * blockDim.x + threadIdx.x;
    if (e >= ETOT) return;
    int src, dst;
    if (e < EE) { src = ei[e]; dst = ei[EE + e]; }
    else        { src = dst = e - EE; }
    csr[offs[dst] + pos[e]] = src;
}

// ---------------- graph boundaries (batch is sorted) ----------------
__global__ void k_bounds(const int* __restrict__ batch, int* __restrict__ gstart) {
    int n = blockIdx.x * blockDim.x + threadIdx.x;
    if (n >= NN) return;
    int b = batch[n];
    if (n == 0) {
        for (int g = 0; g <= b; g++) gstart[g] = 0;
    } else {
        int pb = batch[n - 1];
        for (int g = pb + 1; g <= b; g++) gstart[g] = n;
    }
    if (n == NN - 1) {
        for (int g = b + 1; g <= GG; g++) gstart[g] = NN;
    }
}

// ---------------- GEMM: H = X @ W  ([N,DIN] x [DIN,100]) ----------------
// 256 threads, 32 rows/block, each thread: 4 rows x 4 cols register tile.
template <int DIN>
__global__ __launch_bounds__(256) void k_gemm(const float* __restrict__ X,
                                              const float* __restrict__ W,
                                              float* __restrict__ H) {
    __shared__ float Ws[DIN * 104];        // pad 100 -> 104 for float4 alignment
    __shared__ float Xs[32 * (DIN + 1)];   // +1 pad: bank-conflict-free across rl
    const int tid = threadIdx.x;

    for (int idx = tid; idx < DIN * 100; idx += 256) {
        int k = idx / 100, c = idx - k * 100;
        Ws[k * 104 + c] = W[idx];
    }

    const int node0 = blockIdx.x * 32;
    for (int idx = tid; idx < 32 * DIN; idx += 256) {
        int r = idx / DIN, k = idx - r * DIN;
        int row = node0 + r;
        Xs[r * (DIN + 1) + k] = (row < NN) ? X[(size_t)row * DIN + k] : 0.f;
    }
    __syncthreads();

    const int rl = tid >> 5;    // 0..7
    const int cg = tid & 31;    // 0..31 (25 active)
    if (cg >= 25) return;

    float acc[4][4] = {};
    #pragma unroll 4
    for (int k = 0; k < DIN; k++) {
        float4 w = *reinterpret_cast<const float4*>(&Ws[k * 104 + cg * 4]);
        #pragma unroll
        for (int j = 0; j < 4; j++) {
            float xv = Xs[(rl + 8 * j) * (DIN + 1) + k];
            acc[j][0] += xv * w.x; acc[j][1] += xv * w.y;
            acc[j][2] += xv * w.z; acc[j][3] += xv * w.w;
        }
    }
    #pragma unroll
    for (int j = 0; j < 4; j++) {
        int row = node0 + rl + 8 * j;
        if (row < NN) {
            float4 v = {acc[j][0], acc[j][1], acc[j][2], acc[j][3]};
            *reinterpret_cast<float4*>(&H[(size_t)row * 100 + cg * 4]) = v;
        }
    }
}

// ---------------- per-node attention logits: es/ed ----------------
__global__ void k_esed(const float* __restrict__ H, const float* __restrict__ AS,
                       const float* __restrict__ AD, float* __restrict__ es, float* __restrict__ ed) {
    int t = blockIdx.x * blockDim.x + threadIdx.x;
    if (t >= NN * HEADS) return;
    int n = t >> 2, hd = t & 3;
    const float* hr = H + (size_t)n * 100 + hd * 25;
    const float* as = AS + hd * 25;
    const float* ad = AD + hd * 25;
    float s1 = 0.f, s2 = 0.f;
    #pragma unroll
    for (int d = 0; d < 25; d++) {
        float v = hr[d];
        s1 += v * as[d];
        s2 += v * ad[d];
    }
    es[t] = s1;
    ed[t] = s2;
}

// ---------------- phase A: per-node softmax stats + per-edge weights ----------------
// one wave per node; lane = edge_slot(16) * 4 + head(4)
__global__ __launch_bounds__(256) void k_msum(const float* __restrict__ es,
                                              const float* __restrict__ ed,
                                              const int* __restrict__ offs,
                                              const int* __restrict__ csr,
                                              float* __restrict__ wv) {
    int wid = threadIdx.x >> 6;
    int lane = threadIdx.x & 63;
    int n = blockIdx.x * 4 + wid;
    if (n >= NN) return;
    int el = lane >> 2, hd = lane & 3;
    int beg = offs[n], end = offs[n + 1];
    float edh = ed[n * 4 + hd];
    float m = NEG_INF, s = 0.f;
    for (int e = beg + el; e < end; e += 16) {
        int si = csr[e];
        float a = es[si * 4 + hd] + edh;
        a = (a > 0.f) ? a : 0.2f * a;
        float nm = fmaxf(m, a);
        float sc = __expf(m - nm);       // m=-inf, nm finite -> 0, no NaN
        s = s * sc + __expf(a - nm);
        m = nm;
    }
    // butterfly merge over edge-slot bits (lane bits 2..5)
    #pragma unroll
    for (int mask = 4; mask <= 32; mask <<= 1) {
        float mo = __shfl_xor(m, mask, 64);
        float so = __shfl_xor(s, mask, 64);
        float nm = fmaxf(m, mo);
        float f1 = (m  > NEG_INF) ? __expf(m  - nm) : 0.f;
        float f2 = (mo > NEG_INF) ? __expf(mo - nm) : 0.f;
        s = s * f1 + so * f2;
        m = nm;
    }
    float invs = 1.f / (s + 1e-16f);
    // fused weight pass (coalesced 256B writes per 16 edges)
    for (int e = beg + el; e < end; e += 16) {
        int si = csr[e];
        float a = es[si * 4 + hd] + edh;
        a = (a > 0.f) ? a : 0.2f * a;
        wv[(size_t)e * 4 + hd] = __expf(a - m) * invs;
    }
}

// ---------------- phase B: weighted gather-accumulate (no dependences) ----------------
__global__ __launch_bounds__(128) void k_acc(const float* __restrict__ H,
                                             const float* __restrict__ wv,
                                             const int* __restrict__ offs,
                                             const int* __restrict__ csr,
                                             const float* __restrict__ bias,
                                             float* __restrict__ out) {
    int n = blockIdx.x;
    int d = threadIdx.x;
    if (d >= 100) return;
    int hd = d / 25;
    int beg = offs[n], end = offs[n + 1];
    float acc = 0.f;
    int e = beg;
    for (; e + 4 <= end; e += 4) {
        int s0 = csr[e], s1 = csr[e + 1], s2 = csr[e + 2], s3 = csr[e + 3];
        float w0 = wv[(size_t)e * 4 + hd];
        float w1 = wv[(size_t)(e + 1) * 4 + hd];
        float w2 = wv[(size_t)(e + 2) * 4 + hd];
        float w3 = wv[(size_t)(e + 3) * 4 + hd];
        float x0 = H[(size_t)s0 * 100 + d];
        float x1 = H[(size_t)s1 * 100 + d];
        float x2 = H[(size_t)s2 * 100 + d];
        float x3 = H[(size_t)s3 * 100 + d];
        acc += w0 * x0;
        acc += w1 * x1;
        acc += w2 * x2;
        acc += w3 * x3;
    }
    for (; e < end; ++e) {
        acc += wv[(size_t)e * 4 + hd] * H[(size_t)csr[e] * 100 + d];
    }
    float o = acc + bias[d];
    out[(size_t)n * 100 + d] = fmaxf(o, 0.f);
}

// ---------------- legacy fused agg (fallback when ws too small) ----------------
__global__ __launch_bounds__(128) void k_agg(const float* __restrict__ H, const float* __restrict__ es,
                                             const float* __restrict__ ed, const int* __restrict__ offs,
                                             const int* __restrict__ csr, const float* __restrict__ bias,
                                             float* __restrict__ out) {
    int n = blockIdx.x;
    int d = threadIdx.x;
    __shared__ float edn[4];
    if (d < 4) edn[d] = ed[n * 4 + d];
    __syncthreads();
    if (d >= 100) return;
    int hd = d / 25;
    float edh = edn[hd];
    int beg = offs[n], end = offs[n + 1];
    float m = NEG_INF, s = 0.f, acc = 0.f;
    for (int e = beg; e < end; ++e) {
        int si = csr[e];
        float a = es[si * 4 + hd] + edh;
        a = (a > 0.f) ? a : 0.2f * a;
        float xv = H[(size_t)si * 100 + d];
        float nm = fmaxf(m, a);
        float sc = __expf(m - nm);
        float p  = __expf(a - nm);
        s   = s * sc + p;
        acc = acc * sc + p * xv;
        m = nm;
    }
    float o = acc / (s + 1e-16f) + bias[d];
    out[(size_t)n * 100 + d] = (o > 0.f) ? o : 0.f;
}

// ---------------- global max pool (2-level) ----------------
__global__ void k_pool1(const float* __restrict__ NE, const int* __restrict__ gstart,
                        float* __restrict__ part) {
    int g = blockIdx.x >> 3, c = blockIdx.x & 7;
    int d = threadIdx.x;
    if (d >= 100) return;
    int s0 = gstart[g], s1 = gstart[g + 1];
    int len = s1 - s0;
    int n0 = s0 + (int)((long long)len * c / 8);
    int n1 = s0 + (int)((long long)len * (c + 1) / 8);
    float vm = NEG_INF;
    for (int n = n0; n < n1; n++) vm = fmaxf(vm, NE[(size_t)n * 100 + d]);
    part[(size_t)(g * 8 + c) * 100 + d] = vm;
}

__global__ void k_pool2(const float* __restrict__ part, float* __restrict__ GE) {
    int g = blockIdx.x;
    int d = threadIdx.x;
    if (d >= 100) return;
    float vm = NEG_INF;
    for (int c = 0; c < 8; c++) vm = fmaxf(vm, part[(size_t)(g * 8 + c) * 100 + d]);
    GE[(size_t)g * 100 + d] = vm;
}

// ---------------- prototype head ----------------
__global__ void k_head(const float* __restrict__ GE, const float* __restrict__ P,
                       const float* __restrict__ LW, float* __restrict__ logits,
                       float* __restrict__ probs, float* __restrict__ dist) {
    int g = blockIdx.x;
    __shared__ float ge[100];
    __shared__ float sims[NUM_PROT];
    __shared__ float lg[OUT_DIM];
    int t = threadIdx.x;
    if (t < 100) ge[t] = GE[(size_t)g * 100 + t];
    __syncthreads();
    if (t < NUM_PROT) {
        float dot = 0.f, pn = 0.f, gn = 0.f;
        for (int d = 0; d < 100; d++) {
            float pv = P[t * 100 + d];
            float gv = ge[d];
            dot += gv * pv;
            pn += pv * pv;
            gn += gv * gv;
        }
        float ds = gn - 2.f * dot + pn;
        dist[g * NUM_PROT + t] = ds;
        sims[t] = logf((ds + 1.f) / (ds + 1e-4f));
    }
    __syncthreads();
    if (t < OUT_DIM) {
        float l = 0.f;
        for (int p = 0; p < NUM_PROT; p++) l += sims[p] * LW[t * NUM_PROT + p];
        lg[t] = l;
        logits[g * OUT_DIM + t] = l;
    }
    __syncthreads();
    if (t == 0) {
        float mm = fmaxf(lg[0], lg[1]);
        float e0 = __expf(lg[0] - mm), e1 = __expf(lg[1] - mm);
        float inv = 1.f / (e0 + e1);
        probs[g * OUT_DIM + 0] = e0 * inv;
        probs[g * OUT_DIM + 1] = e1 * inv;
    }
}

extern "C" void kernel_launch(void* const* d_in, const int* in_sizes, int n_in,
                              void* d_out, int out_size, void* d_ws, size_t ws_size,
                              hipStream_t stream) {
    const float* x     = (const float*)d_in[0];
    const int*   ei    = (const int*)d_in[1];
    const int*   batch = (const int*)d_in[2];
    const float* Wm[3]  = {(const float*)d_in[3],  (const float*)d_in[7],  (const float*)d_in[11]};
    const float* ASm[3] = {(const float*)d_in[4],  (const float*)d_in[8],  (const float*)d_in[12]};
    const float* ADm[3] = {(const float*)d_in[5],  (const float*)d_in[9],  (const float*)d_in[13]};
    const float* Bm[3]  = {(const float*)d_in[6],  (const float*)d_in[10], (const float*)d_in[14]};
    const float* P  = (const float*)d_in[15];
    const float* LW = (const float*)d_in[16];

    float* out = (float*)d_out;
    float* logits  = out;                                   // [64,2]
    float* probs   = out + GG * OUT_DIM;                    // [64,2]
    float* nodeEmb = out + 2 * GG * OUT_DIM;                // [N,100]
    float* GE      = nodeEmb + (size_t)NN * DENSE;          // [64,100]
    float* disto   = GE + GG * DENSE;                       // [64,10]

    // workspace carve-up
    char* w = (char*)d_ws;
    size_t off = 0;
    auto carve = [&](size_t bytes) -> void* {
        void* p = w + off;
        off += (bytes + 15) & ~(size_t)15;
        return p;
    };
    float* hA   = (float*)carve((size_t)NN * DENSE * 4);
    float* es   = (float*)carve((size_t)NN * HEADS * 4);
    float* ed   = (float*)carve((size_t)NN * HEADS * 4);
    int* cnt    = (int*)carve((size_t)NN * 4);
    int* offs   = (int*)carve((size_t)(NN + 1) * 4);
    int* pos    = (int*)carve((size_t)ETOT * 4);
    int* csr    = (int*)carve((size_t)ETOT * 4);
    int* csum   = (int*)carve((size_t)(NCHUNK + 1) * 4);
    int* gstart = (int*)carve((size_t)(GG + 1) * 4);
    float* part = (float*)carve((size_t)GG * 8 * DENSE * 4);
    size_t base_need = off;
    float* wv   = (float*)carve((size_t)ETOT * HEADS * 4);   // per-edge weights
    bool has_wv = (off <= ws_size);
    (void)in_sizes; (void)n_in; (void)out_size; (void)base_need;

    // ---- CSR build (once, reused for all 3 layers) ----
    hipMemsetAsync(cnt, 0, (size_t)NN * 4, stream);
    k_count<<<(ETOT + 255) / 256, 256, 0, stream>>>(ei, cnt, pos);
    k_scan1<<<NCHUNK, 256, 0, stream>>>(cnt, csum);
    k_scan2<<<1, 256, 0, stream>>>(csum);
    k_scan3<<<NCHUNK, 256, 0, stream>>>(cnt, csum, offs);
    k_scatter<<<(ETOT + 255) / 256, 256, 0, stream>>>(ei, offs, pos, csr);
    k_bounds<<<(NN + 255) / 256, 256, 0, stream>>>(batch, gstart);

    const int gemmGrid = (NN + 31) / 32;
    const int esedGrid = (NN * HEADS + 255) / 256;
    const int msumGrid = (NN + 3) / 4;

    const float* layerIn = x;
    for (int l = 0; l < 3; ++l) {
        if (l == 0) k_gemm<IN_DIM><<<gemmGrid, 256, 0, stream>>>(layerIn, Wm[l], hA);
        else        k_gemm<DENSE ><<<gemmGrid, 256, 0, stream>>>(layerIn, Wm[l], hA);
        k_esed<<<esedGrid, 256, 0, stream>>>(hA, ASm[l], ADm[l], es, ed);
        if (has_wv) {
            k_msum<<<msumGrid, 256, 0, stream>>>(es, ed, offs, csr, wv);
            k_acc<<<NN, 128, 0, stream>>>(hA, wv, offs, csr, Bm[l], nodeEmb);
        } else {
            k_agg<<<NN, 128, 0, stream>>>(hA, es, ed, offs, csr, Bm[l], nodeEmb);
        }
        layerIn = nodeEmb;
    }

    // ---- pooling ----
    k_pool1<<<GG * 8, 128, 0, stream>>>(nodeEmb, gstart, part);
    k_pool2<<<GG, 128, 0, stream>>>(part, GE);

    // ---- prototype head ----
    k_head<<<GG, 128, 0, stream>>>(GE, P, LW, logits, probs, disto);
}

// Round 3
// 483.589 us; speedup vs baseline: 1.2522x; 1.0200x over previous
//
#include <hip/hip_runtime.h>
#include <hip/hip_bf16.h>

#define NN      50000
#define EE      800000
#define ETOT    (EE + NN)        // + self loops
#define GG      64
#define HEADS   4
#define HID     25
#define DENSE   100
#define IN_DIM  128
#define OUT_DIM 2
#define NPC     5
#define NUM_PROT (OUT_DIM * NPC)
#define NCHUNK  ((NN + 255) / 256)

#define NEG_INF (-3.402823466e38f)

// ---------------- CSR build ----------------
__global__ void k_count(const int* __restrict__ ei, int* __restrict__ cnt, int* __restrict__ pos) {
    int e = blockIdx.x * blockDim.x + threadIdx.x;
    if (e >= ETOT) return;
    int dst = (e < EE) ? ei[EE + e] : (e - EE);
    pos[e] = atomicAdd(&cnt[dst], 1);
}

__global__ void k_scan1(const int* __restrict__ cnt, int* __restrict__ csum) {
    __shared__ int sh[256];
    int i = blockIdx.x * 256 + threadIdx.x;
    int v = (i < NN) ? cnt[i] : 0;
    sh[threadIdx.x] = v;
    __syncthreads();
    for (int s = 128; s > 0; s >>= 1) {
        if (threadIdx.x < s) sh[threadIdx.x] += sh[threadIdx.x + s];
        __syncthreads();
    }
    if (threadIdx.x == 0) csum[blockIdx.x] = sh[0];
}

__global__ void k_scan2(int* __restrict__ csum) {
    __shared__ int sh[256];
    int tid = threadIdx.x;
    int v = (tid < NCHUNK) ? csum[tid] : 0;
    sh[tid] = v;
    __syncthreads();
    for (int s = 1; s < 256; s <<= 1) {
        int t = (tid >= s) ? sh[tid - s] : 0;
        __syncthreads();
        sh[tid] += t;
        __syncthreads();
    }
    if (tid < NCHUNK) csum[tid] = sh[tid] - v;     // exclusive
    if (tid == NCHUNK) csum[NCHUNK] = sh[255];     // total
}

__global__ void k_scan3(const int* __restrict__ cnt, const int* __restrict__ csum, int* __restrict__ offs) {
    __shared__ int sh[256];
    int i = blockIdx.x * 256 + threadIdx.x;
    int v = (i < NN) ? cnt[i] : 0;
    sh[threadIdx.x] = v;
    __syncthreads();
    for (int s = 1; s < 256; s <<= 1) {
        int t = (threadIdx.x >= s) ? sh[threadIdx.x - s] : 0;
        __syncthreads();
        sh[threadIdx.x] += t;
        __syncthreads();
    }
    int excl = sh[threadIdx.x] - v + csum[blockIdx.x];
    if (i <= NN) offs[i] = excl;
}

__global__ void k_scatter(const int* __restrict__ ei, const int* __restrict__ offs,
                          const int* __restrict__ pos, int* __restrict__ csr) {
    int e = blockIdx.x * blockDim.x + threadIdx.x;
    if (e >= ETOT) return;
    int src, dst;
    if (e < EE) { src = ei[e]; dst = ei[EE + e]; }
    else        { src = dst = e - EE; }
    csr[offs[dst] + pos[e]] = src;
}

// ---------------- graph boundaries (batch is sorted) ----------------
__global__ void k_bounds(const int* __restrict__ batch, int* __restrict__ gstart) {
    int n = blockIdx.x * blockDim.x + threadIdx.x;
    if (n >= NN) return;
    int b = batch[n];
    if (n == 0) {
        for (int g = 0; g <= b; g++) gstart[g] = 0;
    } else {
        int pb = batch[n - 1];
        for (int g = pb + 1; g <= b; g++) gstart[g] = n;
    }
    if (n == NN - 1) {
        for (int g = b + 1; g <= GG; g++) gstart[g] = NN;
    }
}

// ---------------- GEMM: H = X @ W  ([N,DIN] x [DIN,100]) ----------------
// 256 threads, 32 rows/block, 4 rows x 4 cols register tile per thread,
// K staged in KC-chunks to keep LDS small (8 blocks/CU occupancy).
template <int DIN, int KC>
__global__ __launch_bounds__(256) void k_gemm(const float* __restrict__ X,
                                              const float* __restrict__ W,
                                              float* __restrict__ H) {
    __shared__ float Ws[KC * 104];        // pad 100 -> 104 for float4 alignment
    __shared__ float Xs[32 * (KC + 1)];
    const int tid = threadIdx.x;
    const int rl = tid >> 5;    // 0..7
    const int cg = tid & 31;    // 0..31 (25 active)
    const int node0 = blockIdx.x * 32;

    float acc[4][4] = {};
    constexpr int NCH = DIN / KC;         // exact: 128/32, 100/25
    for (int kb = 0; kb < NCH; ++kb) {
        const int k0 = kb * KC;
        for (int idx = tid; idx < KC * 100; idx += 256) {
            int k = idx / 100, c = idx - k * 100;
            Ws[k * 104 + c] = W[(k0 + k) * 100 + c];
        }
        for (int idx = tid; idx < 32 * KC; idx += 256) {
            int r = idx / KC, k = idx - r * KC;
            int row = node0 + r;
            Xs[r * (KC + 1) + k] = (row < NN) ? X[(size_t)row * DIN + k0 + k] : 0.f;
        }
        __syncthreads();
        if (cg < 25) {
            #pragma unroll
            for (int k = 0; k < KC; ++k) {
                float4 w = *reinterpret_cast<const float4*>(&Ws[k * 104 + cg * 4]);
                #pragma unroll
                for (int j = 0; j < 4; ++j) {
                    float xv = Xs[(rl + 8 * j) * (KC + 1) + k];
                    acc[j][0] += xv * w.x; acc[j][1] += xv * w.y;
                    acc[j][2] += xv * w.z; acc[j][3] += xv * w.w;
                }
            }
        }
        __syncthreads();
    }
    if (cg < 25) {
        #pragma unroll
        for (int j = 0; j < 4; ++j) {
            int row = node0 + rl + 8 * j;
            if (row < NN) {
                float4 v = {acc[j][0], acc[j][1], acc[j][2], acc[j][3]};
                *reinterpret_cast<float4*>(&H[(size_t)row * 100 + cg * 4]) = v;
            }
        }
    }
}

// ---------------- per-node attention logits: es/ed ----------------
__global__ void k_esed(const float* __restrict__ H, const float* __restrict__ AS,
                       const float* __restrict__ AD, float* __restrict__ es, float* __restrict__ ed) {
    int t = blockIdx.x * blockDim.x + threadIdx.x;
    if (t >= NN * HEADS) return;
    int n = t >> 2, hd = t & 3;
    const float* hr = H + (size_t)n * 100 + hd * 25;
    const float* as = AS + hd * 25;
    const float* ad = AD + hd * 25;
    float s1 = 0.f, s2 = 0.f;
    #pragma unroll
    for (int d = 0; d < 25; d++) {
        float v = hr[d];
        s1 += v * as[d];
        s2 += v * ad[d];
    }
    es[t] = s1;
    ed[t] = s2;
}

// ---------------- phase A: per-node softmax stats + per-edge weights ----------------
// one wave per node; lane = edge_slot(16) * 4 + head(4)
__global__ __launch_bounds__(256) void k_msum(const float* __restrict__ es,
                                              const float* __restrict__ ed,
                                              const int* __restrict__ offs,
                                              const int* __restrict__ csr,
                                              float* __restrict__ wv) {
    int wid = threadIdx.x >> 6;
    int lane = threadIdx.x & 63;
    int n = blockIdx.x * 4 + wid;
    if (n >= NN) return;
    int el = lane >> 2, hd = lane & 3;
    int beg = offs[n], end = offs[n + 1];
    float edh = ed[n * 4 + hd];
    float m = NEG_INF, s = 0.f;
    for (int e = beg + el; e < end; e += 16) {
        int si = csr[e];
        float a = es[si * 4 + hd] + edh;
        a = (a > 0.f) ? a : 0.2f * a;
        float nm = fmaxf(m, a);
        float sc = __expf(m - nm);       // m=-inf, nm finite -> 0, no NaN
        s = s * sc + __expf(a - nm);
        m = nm;
    }
    // butterfly merge over edge-slot bits (lane bits 2..5)
    #pragma unroll
    for (int mask = 4; mask <= 32; mask <<= 1) {
        float mo = __shfl_xor(m, mask, 64);
        float so = __shfl_xor(s, mask, 64);
        float nm = fmaxf(m, mo);
        float f1 = (m  > NEG_INF) ? __expf(m  - nm) : 0.f;
        float f2 = (mo > NEG_INF) ? __expf(mo - nm) : 0.f;
        s = s * f1 + so * f2;
        m = nm;
    }
    float invs = 1.f / (s + 1e-16f);
    // fused weight pass (coalesced 256B writes per 16 edges)
    for (int e = beg + el; e < end; e += 16) {
        int si = csr[e];
        float a = es[si * 4 + hd] + edh;
        a = (a > 0.f) ? a : 0.2f * a;
        wv[(size_t)e * 4 + hd] = __expf(a - m) * invs;
    }
}

// ---------------- phase B: weighted gather-accumulate ----------------
// 2 nodes per block (1 wave each); 50 lanes x float2 = one 400B row per request
__global__ __launch_bounds__(128) void k_acc(const float* __restrict__ H,
                                             const float* __restrict__ wv,
                                             const int* __restrict__ offs,
                                             const int* __restrict__ csr,
                                             const float* __restrict__ bias,
                                             float* __restrict__ out) {
    int wid = threadIdx.x >> 6;
    int lane = threadIdx.x & 63;
    int n = blockIdx.x * 2 + wid;
    if (n >= NN || lane >= 50) return;
    int d0 = lane * 2;
    int h0 = d0 / 25, h1 = (d0 + 1) / 25;
    int beg = offs[n], end = offs[n + 1];
    float ax = 0.f, ay = 0.f;
    int e = beg;
    for (; e + 4 <= end; e += 4) {
        int s0 = csr[e], s1 = csr[e + 1], s2 = csr[e + 2], s3 = csr[e + 3];
        float2 x0 = *reinterpret_cast<const float2*>(&H[(size_t)s0 * 100 + d0]);
        float2 x1 = *reinterpret_cast<const float2*>(&H[(size_t)s1 * 100 + d0]);
        float2 x2 = *reinterpret_cast<const float2*>(&H[(size_t)s2 * 100 + d0]);
        float2 x3 = *reinterpret_cast<const float2*>(&H[(size_t)s3 * 100 + d0]);
        float w0x = wv[(size_t)e * 4 + h0],       w0y = wv[(size_t)e * 4 + h1];
        float w1x = wv[(size_t)(e + 1) * 4 + h0], w1y = wv[(size_t)(e + 1) * 4 + h1];
        float w2x = wv[(size_t)(e + 2) * 4 + h0], w2y = wv[(size_t)(e + 2) * 4 + h1];
        float w3x = wv[(size_t)(e + 3) * 4 + h0], w3y = wv[(size_t)(e + 3) * 4 + h1];
        ax += w0x * x0.x; ay += w0y * x0.y;
        ax += w1x * x1.x; ay += w1y * x1.y;
        ax += w2x * x2.x; ay += w2y * x2.y;
        ax += w3x * x3.x; ay += w3y * x3.y;
    }
    for (; e < end; ++e) {
        float2 xv = *reinterpret_cast<const float2*>(&H[(size_t)csr[e] * 100 + d0]);
        ax += wv[(size_t)e * 4 + h0] * xv.x;
        ay += wv[(size_t)e * 4 + h1] * xv.y;
    }
    float2 b = *reinterpret_cast<const float2*>(&bias[d0]);
    float2 o = {fmaxf(ax + b.x, 0.f), fmaxf(ay + b.y, 0.f)};
    *reinterpret_cast<float2*>(&out[(size_t)n * 100 + d0]) = o;
}

// ---------------- global max pool (2-level) ----------------
__global__ void k_pool1(const float* __restrict__ NE, const int* __restrict__ gstart,
                        float* __restrict__ part) {
    int g = blockIdx.x >> 3, c = blockIdx.x & 7;
    int d = threadIdx.x;
    if (d >= 100) return;
    int s0 = gstart[g], s1 = gstart[g + 1];
    int len = s1 - s0;
    int n0 = s0 + (int)((long long)len * c / 8);
    int n1 = s0 + (int)((long long)len * (c + 1) / 8);
    float vm = NEG_INF;
    for (int n = n0; n < n1; n++) vm = fmaxf(vm, NE[(size_t)n * 100 + d]);
    part[(size_t)(g * 8 + c) * 100 + d] = vm;
}

__global__ void k_pool2(const float* __restrict__ part, float* __restrict__ GE) {
    int g = blockIdx.x;
    int d = threadIdx.x;
    if (d >= 100) return;
    float vm = NEG_INF;
    for (int c = 0; c < 8; c++) vm = fmaxf(vm, part[(size_t)(g * 8 + c) * 100 + d]);
    GE[(size_t)g * 100 + d] = vm;
}

// ---------------- prototype head ----------------
__global__ void k_head(const float* __restrict__ GE, const float* __restrict__ P,
                       const float* __restrict__ LW, float* __restrict__ logits,
                       float* __restrict__ probs, float* __restrict__ dist) {
    int g = blockIdx.x;
    __shared__ float ge[100];
    __shared__ float sims[NUM_PROT];
    __shared__ float lg[OUT_DIM];
    int t = threadIdx.x;
    if (t < 100) ge[t] = GE[(size_t)g * 100 + t];
    __syncthreads();
    if (t < NUM_PROT) {
        float dot = 0.f, pn = 0.f, gn = 0.f;
        for (int d = 0; d < 100; d++) {
            float pv = P[t * 100 + d];
            float gv = ge[d];
            dot += gv * pv;
            pn += pv * pv;
            gn += gv * gv;
        }
        float ds = gn - 2.f * dot + pn;
        dist[g * NUM_PROT + t] = ds;
        sims[t] = logf((ds + 1.f) / (ds + 1e-4f));
    }
    __syncthreads();
    if (t < OUT_DIM) {
        float l = 0.f;
        for (int p = 0; p < NUM_PROT; p++) l += sims[p] * LW[t * NUM_PROT + p];
        lg[t] = l;
        logits[g * OUT_DIM + t] = l;
    }
    __syncthreads();
    if (t == 0) {
        float mm = fmaxf(lg[0], lg[1]);
        float e0 = __expf(lg[0] - mm), e1 = __expf(lg[1] - mm);
        float inv = 1.f / (e0 + e1);
        probs[g * OUT_DIM + 0] = e0 * inv;
        probs[g * OUT_DIM + 1] = e1 * inv;
    }
}

extern "C" void kernel_launch(void* const* d_in, const int* in_sizes, int n_in,
                              void* d_out, int out_size, void* d_ws, size_t ws_size,
                              hipStream_t stream) {
    const float* x     = (const float*)d_in[0];
    const int*   ei    = (const int*)d_in[1];
    const int*   batch = (const int*)d_in[2];
    const float* Wm[3]  = {(const float*)d_in[3],  (const float*)d_in[7],  (const float*)d_in[11]};
    const float* ASm[3] = {(const float*)d_in[4],  (const float*)d_in[8],  (const float*)d_in[12]};
    const float* ADm[3] = {(const float*)d_in[5],  (const float*)d_in[9],  (const float*)d_in[13]};
    const float* Bm[3]  = {(const float*)d_in[6],  (const float*)d_in[10], (const float*)d_in[14]};
    const float* P  = (const float*)d_in[15];
    const float* LW = (const float*)d_in[16];

    float* out = (float*)d_out;
    float* logits  = out;                                   // [64,2]
    float* probs   = out + GG * OUT_DIM;                    // [64,2]
    float* nodeEmb = out + 2 * GG * OUT_DIM;                // [N,100]
    float* GE      = nodeEmb + (size_t)NN * DENSE;          // [64,100]
    float* disto   = GE + GG * DENSE;                       // [64,10]

    // workspace carve-up
    char* w = (char*)d_ws;
    size_t off = 0;
    auto carve = [&](size_t bytes) -> void* {
        void* p = w + off;
        off += (bytes + 15) & ~(size_t)15;
        return p;
    };
    float* hA   = (float*)carve((size_t)NN * DENSE * 4);
    float* es   = (float*)carve((size_t)NN * HEADS * 4);
    float* ed   = (float*)carve((size_t)NN * HEADS * 4);
    int* cnt    = (int*)carve((size_t)NN * 4);
    int* offs   = (int*)carve((size_t)(NN + 1) * 4);
    int* pos    = (int*)carve((size_t)ETOT * 4);
    int* csr    = (int*)carve((size_t)ETOT * 4);
    int* csum   = (int*)carve((size_t)(NCHUNK + 1) * 4);
    int* gstart = (int*)carve((size_t)(GG + 1) * 4);
    float* part = (float*)carve((size_t)GG * 8 * DENSE * 4);
    float* wv   = (float*)carve((size_t)ETOT * HEADS * 4);   // per-edge weights
    bool has_wv = (off <= ws_size);
    (void)in_sizes; (void)n_in; (void)out_size;

    // ---- CSR build (once, reused for all 3 layers) ----
    hipMemsetAsync(cnt, 0, (size_t)NN * 4, stream);
    k_count<<<(ETOT + 255) / 256, 256, 0, stream>>>(ei, cnt, pos);
    k_scan1<<<NCHUNK, 256, 0, stream>>>(cnt, csum);
    k_scan2<<<1, 256, 0, stream>>>(csum);
    k_scan3<<<NCHUNK, 256, 0, stream>>>(cnt, csum, offs);
    k_scatter<<<(ETOT + 255) / 256, 256, 0, stream>>>(ei, offs, pos, csr);
    k_bounds<<<(NN + 255) / 256, 256, 0, stream>>>(batch, gstart);

    const int gemmGrid = (NN + 31) / 32;
    const int esedGrid = (NN * HEADS + 255) / 256;
    const int msumGrid = (NN + 3) / 4;
    const int accGrid  = (NN + 1) / 2;

    const float* layerIn = x;
    for (int l = 0; l < 3; ++l) {
        if (l == 0) k_gemm<IN_DIM, 32><<<gemmGrid, 256, 0, stream>>>(layerIn, Wm[l], hA);
        else        k_gemm<DENSE,  25><<<gemmGrid, 256, 0, stream>>>(layerIn, Wm[l], hA);
        k_esed<<<esedGrid, 256, 0, stream>>>(hA, ASm[l], ADm[l], es, ed);
        k_msum<<<msumGrid, 256, 0, stream>>>(es, ed, offs, csr, wv);
        k_acc<<<accGrid, 128, 0, stream>>>(hA, wv, offs, csr, Bm[l], nodeEmb);
        layerIn = nodeEmb;
        (void)has_wv;
    }

    // ---- pooling ----
    k_pool1<<<GG * 8, 128, 0, stream>>>(nodeEmb, gstart, part);
    k_pool2<<<GG, 128, 0, stream>>>(part, GE);

    // ---- prototype head ----
    k_head<<<GG, 128, 0, stream>>>(GE, P, LW, logits, probs, disto);
}

// Round 4
// 457.721 us; speedup vs baseline: 1.3229x; 1.0565x over previous
//
#include <hip/hip_runtime.h>
#include <hip/hip_bf16.h>

#define NN      50000
#define EE      800000
#define ETOT    (EE + NN)        // + self loops
#define GG      64
#define HEADS   4
#define HID     25
#define DENSE   100
#define IN_DIM  128
#define OUT_DIM 2
#define NPC     5
#define NUM_PROT (OUT_DIM * NPC)
#define NCHUNK  ((NN + 255) / 256)

#define NEG_INF (-3.402823466e38f)

// ---------------- CSR build ----------------
__global__ void k_count(const int* __restrict__ ei, int* __restrict__ cnt, int* __restrict__ pos) {
    int e = blockIdx.x * blockDim.x + threadIdx.x;
    if (e >= ETOT) return;
    int dst = (e < EE) ? ei[EE + e] : (e - EE);
    pos[e] = atomicAdd(&cnt[dst], 1);
}

__global__ void k_scan1(const int* __restrict__ cnt, int* __restrict__ csum) {
    __shared__ int sh[256];
    int i = blockIdx.x * 256 + threadIdx.x;
    int v = (i < NN) ? cnt[i] : 0;
    sh[threadIdx.x] = v;
    __syncthreads();
    for (int s = 128; s > 0; s >>= 1) {
        if (threadIdx.x < s) sh[threadIdx.x] += sh[threadIdx.x + s];
        __syncthreads();
    }
    if (threadIdx.x == 0) csum[blockIdx.x] = sh[0];
}

__global__ void k_scan2(int* __restrict__ csum) {
    __shared__ int sh[256];
    int tid = threadIdx.x;
    int v = (tid < NCHUNK) ? csum[tid] : 0;
    sh[tid] = v;
    __syncthreads();
    for (int s = 1; s < 256; s <<= 1) {
        int t = (tid >= s) ? sh[tid - s] : 0;
        __syncthreads();
        sh[tid] += t;
        __syncthreads();
    }
    if (tid < NCHUNK) csum[tid] = sh[tid] - v;     // exclusive
    if (tid == NCHUNK) csum[NCHUNK] = sh[255];     // total
}

__global__ void k_scan3(const int* __restrict__ cnt, const int* __restrict__ csum, int* __restrict__ offs) {
    __shared__ int sh[256];
    int i = blockIdx.x * 256 + threadIdx.x;
    int v = (i < NN) ? cnt[i] : 0;
    sh[threadIdx.x] = v;
    __syncthreads();
    for (int s = 1; s < 256; s <<= 1) {
        int t = (threadIdx.x >= s) ? sh[threadIdx.x - s] : 0;
        __syncthreads();
        sh[threadIdx.x] += t;
        __syncthreads();
    }
    int excl = sh[threadIdx.x] - v + csum[blockIdx.x];
    if (i <= NN) offs[i] = excl;
}

__global__ void k_scatter(const int* __restrict__ ei, const int* __restrict__ offs,
                          const int* __restrict__ pos, int* __restrict__ csr) {
    int e = blockIdx.x * blockDim.x + threadIdx.x;
    if (e >= ETOT) return;
    int src, dst;
    if (e < EE) { src = ei[e]; dst = ei[EE + e]; }
    else        { src = dst = e - EE; }
    csr[offs[dst] + pos[e]] = src;
}

// ---------------- graph boundaries (batch is sorted) ----------------
__global__ void k_bounds(const int* __restrict__ batch, int* __restrict__ gstart) {
    int n = blockIdx.x * blockDim.x + threadIdx.x;
    if (n >= NN) return;
    int b = batch[n];
    if (n == 0) {
        for (int g = 0; g <= b; g++) gstart[g] = 0;
    } else {
        int pb = batch[n - 1];
        for (int g = pb + 1; g <= b; g++) gstart[g] = n;
    }
    if (n == NN - 1) {
        for (int g = b + 1; g <= GG; g++) gstart[g] = NN;
    }
}

// ---------------- GEMM: H = X @ W  ([N,DIN] x [DIN,100]) ----------------
// 256 threads, 128 rows/block, 16 rows x 4 cols per thread.
// Xs reads are half-wave-uniform b128 (broadcast); Ws b128 per k.
// FMA:LDS-instr ratio = 256:20 per 4-k step -> FMA-bound.
template <int DIN, int KC>
__global__ __launch_bounds__(256) void k_gemm(const float* __restrict__ X,
                                              const float* __restrict__ W,
                                              float* __restrict__ H) {
    constexpr int XSTR = KC + 4;          // row stride in floats (16B-aligned, bank-skewed)
    __shared__ float Ws[KC * 104];        // pad 100 -> 104
    __shared__ float Xs[128 * XSTR];
    const int tid = threadIdx.x;
    const int rl = tid >> 5;    // 0..7  -> rows rl*16 .. rl*16+15
    const int cg = tid & 31;    // 0..31 (25 active)
    const int node0 = blockIdx.x * 128;

    float acc[16][4] = {};
    constexpr int NCH = DIN / KC;         // exact: 128/32, 100/20
    constexpr int KQ = KC / 4;
    for (int kb = 0; kb < NCH; ++kb) {
        const int k0 = kb * KC;
        // stage W chunk (coalesced, contiguous region of W)
        for (int idx = tid; idx < KC * 100; idx += 256) {
            int k = idx / 100, c = idx - k * 100;
            Ws[k * 104 + c] = W[(k0 + k) * 100 + c];
        }
        // stage X chunk: 128 rows x KC floats, float4 granules
        for (int q = tid; q < 128 * KQ; q += 256) {
            int r = q / KQ, kq = q - r * KQ;
            int row = node0 + r;
            float4 v = {0.f, 0.f, 0.f, 0.f};
            if (row < NN) v = *reinterpret_cast<const float4*>(&X[(size_t)row * DIN + k0 + kq * 4]);
            *reinterpret_cast<float4*>(&Xs[r * XSTR + kq * 4]) = v;
        }
        __syncthreads();
        if (cg < 25) {
            for (int kq = 0; kq < KQ; ++kq) {
                float4 w0 = *reinterpret_cast<const float4*>(&Ws[(kq * 4 + 0) * 104 + cg * 4]);
                float4 w1 = *reinterpret_cast<const float4*>(&Ws[(kq * 4 + 1) * 104 + cg * 4]);
                float4 w2 = *reinterpret_cast<const float4*>(&Ws[(kq * 4 + 2) * 104 + cg * 4]);
                float4 w3 = *reinterpret_cast<const float4*>(&Ws[(kq * 4 + 3) * 104 + cg * 4]);
                #pragma unroll
                for (int j = 0; j < 16; ++j) {
                    float4 xv = *reinterpret_cast<const float4*>(&Xs[(rl * 16 + j) * XSTR + kq * 4]);
                    acc[j][0] += xv.x * w0.x; acc[j][1] += xv.x * w0.y;
                    acc[j][2] += xv.x * w0.z; acc[j][3] += xv.x * w0.w;
                    acc[j][0] += xv.y * w1.x; acc[j][1] += xv.y * w1.y;
                    acc[j][2] += xv.y * w1.z; acc[j][3] += xv.y * w1.w;
                    acc[j][0] += xv.z * w2.x; acc[j][1] += xv.z * w2.y;
                    acc[j][2] += xv.z * w2.z; acc[j][3] += xv.z * w2.w;
                    acc[j][0] += xv.w * w3.x; acc[j][1] += xv.w * w3.y;
                    acc[j][2] += xv.w * w3.z; acc[j][3] += xv.w * w3.w;
                }
            }
        }
        __syncthreads();
    }
    if (cg < 25) {
        #pragma unroll
        for (int j = 0; j < 16; ++j) {
            int row = node0 + rl * 16 + j;
            if (row < NN) {
                float4 v = {acc[j][0], acc[j][1], acc[j][2], acc[j][3]};
                *reinterpret_cast<float4*>(&H[(size_t)row * 100 + cg * 4]) = v;
            }
        }
    }
}

// ---------------- per-node attention logits: es/ed ----------------
__global__ void k_esed(const float* __restrict__ H, const float* __restrict__ AS,
                       const float* __restrict__ AD, float* __restrict__ es, float* __restrict__ ed) {
    int t = blockIdx.x * blockDim.x + threadIdx.x;
    if (t >= NN * HEADS) return;
    int n = t >> 2, hd = t & 3;
    const float* hr = H + (size_t)n * 100 + hd * 25;
    const float* as = AS + hd * 25;
    const float* ad = AD + hd * 25;
    float s1 = 0.f, s2 = 0.f;
    #pragma unroll
    for (int d = 0; d < 25; d++) {
        float v = hr[d];
        s1 += v * as[d];
        s2 += v * ad[d];
    }
    es[t] = s1;
    ed[t] = s2;
}

// ---------------- phase A: per-node softmax stats + per-edge weights ----------------
// one wave per node; lane = edge_slot(16) * 4 + head(4)
__global__ __launch_bounds__(256) void k_msum(const float* __restrict__ es,
                                              const float* __restrict__ ed,
                                              const int* __restrict__ offs,
                                              const int* __restrict__ csr,
                                              float* __restrict__ wv) {
    int wid = threadIdx.x >> 6;
    int lane = threadIdx.x & 63;
    int n = blockIdx.x * 4 + wid;
    if (n >= NN) return;
    int el = lane >> 2, hd = lane & 3;
    int beg = offs[n], end = offs[n + 1];
    float edh = ed[n * 4 + hd];
    float m = NEG_INF, s = 0.f;
    for (int e = beg + el; e < end; e += 16) {
        int si = csr[e];
        float a = es[si * 4 + hd] + edh;
        a = (a > 0.f) ? a : 0.2f * a;
        float nm = fmaxf(m, a);
        float sc = __expf(m - nm);       // m=-inf, nm finite -> 0, no NaN
        s = s * sc + __expf(a - nm);
        m = nm;
    }
    // butterfly merge over edge-slot bits (lane bits 2..5)
    #pragma unroll
    for (int mask = 4; mask <= 32; mask <<= 1) {
        float mo = __shfl_xor(m, mask, 64);
        float so = __shfl_xor(s, mask, 64);
        float nm = fmaxf(m, mo);
        float f1 = (m  > NEG_INF) ? __expf(m  - nm) : 0.f;
        float f2 = (mo > NEG_INF) ? __expf(mo - nm) : 0.f;
        s = s * f1 + so * f2;
        m = nm;
    }
    float invs = 1.f / (s + 1e-16f);
    // fused weight pass (coalesced 256B writes per 16 edges)
    for (int e = beg + el; e < end; e += 16) {
        int si = csr[e];
        float a = es[si * 4 + hd] + edh;
        a = (a > 0.f) ? a : 0.2f * a;
        wv[(size_t)e * 4 + hd] = __expf(a - m) * invs;
    }
}

// ---------------- phase B: weighted gather-accumulate ----------------
// 2 nodes per block (1 wave each); 50 lanes x float2 = one 400B row per request.
// Predicated unroll-8: 8 independent gathers always in flight, no serial tail.
__global__ __launch_bounds__(128) void k_acc(const float* __restrict__ H,
                                             const float* __restrict__ wv,
                                             const int* __restrict__ offs,
                                             const int* __restrict__ csr,
                                             const float* __restrict__ bias,
                                             float* __restrict__ out) {
    int wid = threadIdx.x >> 6;
    int lane = threadIdx.x & 63;
    int n = blockIdx.x * 2 + wid;
    if (n >= NN || lane >= 50) return;
    int d0 = lane * 2;
    int h0 = d0 / 25, h1 = (d0 + 1) / 25;
    int beg = offs[n], end = offs[n + 1];
    float ax = 0.f, ay = 0.f;
    for (int e = beg; e < end; e += 8) {
        #pragma unroll
        for (int u = 0; u < 8; ++u) {
            int ee = e + u;
            int ec = (ee < end) ? ee : beg;          // clamp to a valid slot
            int idx = csr[ec];
            float wx = wv[(size_t)ec * 4 + h0];
            float wy = wv[(size_t)ec * 4 + h1];
            if (ee >= end) { wx = 0.f; wy = 0.f; }   // zero weight for phantom lanes
            float2 xv = *reinterpret_cast<const float2*>(&H[(size_t)idx * 100 + d0]);
            ax += wx * xv.x;
            ay += wy * xv.y;
        }
    }
    float2 b = *reinterpret_cast<const float2*>(&bias[d0]);
    float2 o = {fmaxf(ax + b.x, 0.f), fmaxf(ay + b.y, 0.f)};
    *reinterpret_cast<float2*>(&out[(size_t)n * 100 + d0]) = o;
}

// ---------------- global max pool (2-level) ----------------
__global__ void k_pool1(const float* __restrict__ NE, const int* __restrict__ gstart,
                        float* __restrict__ part) {
    int g = blockIdx.x >> 3, c = blockIdx.x & 7;
    int d = threadIdx.x;
    if (d >= 100) return;
    int s0 = gstart[g], s1 = gstart[g + 1];
    int len = s1 - s0;
    int n0 = s0 + (int)((long long)len * c / 8);
    int n1 = s0 + (int)((long long)len * (c + 1) / 8);
    float vm = NEG_INF;
    for (int n = n0; n < n1; n++) vm = fmaxf(vm, NE[(size_t)n * 100 + d]);
    part[(size_t)(g * 8 + c) * 100 + d] = vm;
}

__global__ void k_pool2(const float* __restrict__ part, float* __restrict__ GE) {
    int g = blockIdx.x;
    int d = threadIdx.x;
    if (d >= 100) return;
    float vm = NEG_INF;
    for (int c = 0; c < 8; c++) vm = fmaxf(vm, part[(size_t)(g * 8 + c) * 100 + d]);
    GE[(size_t)g * 100 + d] = vm;
}

// ---------------- prototype head ----------------
__global__ void k_head(const float* __restrict__ GE, const float* __restrict__ P,
                       const float* __restrict__ LW, float* __restrict__ logits,
                       float* __restrict__ probs, float* __restrict__ dist) {
    int g = blockIdx.x;
    __shared__ float ge[100];
    __shared__ float sims[NUM_PROT];
    __shared__ float lg[OUT_DIM];
    int t = threadIdx.x;
    if (t < 100) ge[t] = GE[(size_t)g * 100 + t];
    __syncthreads();
    if (t < NUM_PROT) {
        float dot = 0.f, pn = 0.f, gn = 0.f;
        for (int d = 0; d < 100; d++) {
            float pv = P[t * 100 + d];
            float gv = ge[d];
            dot += gv * pv;
            pn += pv * pv;
            gn += gv * gv;
        }
        float ds = gn - 2.f * dot + pn;
        dist[g * NUM_PROT + t] = ds;
        sims[t] = logf((ds + 1.f) / (ds + 1e-4f));
    }
    __syncthreads();
    if (t < OUT_DIM) {
        float l = 0.f;
        for (int p = 0; p < NUM_PROT; p++) l += sims[p] * LW[t * NUM_PROT + p];
        lg[t] = l;
        logits[g * OUT_DIM + t] = l;
    }
    __syncthreads();
    if (t == 0) {
        float mm = fmaxf(lg[0], lg[1]);
        float e0 = __expf(lg[0] - mm), e1 = __expf(lg[1] - mm);
        float inv = 1.f / (e0 + e1);
        probs[g * OUT_DIM + 0] = e0 * inv;
        probs[g * OUT_DIM + 1] = e1 * inv;
    }
}

extern "C" void kernel_launch(void* const* d_in, const int* in_sizes, int n_in,
                              void* d_out, int out_size, void* d_ws, size_t ws_size,
                              hipStream_t stream) {
    const float* x     = (const float*)d_in[0];
    const int*   ei    = (const int*)d_in[1];
    const int*   batch = (const int*)d_in[2];
    const float* Wm[3]  = {(const float*)d_in[3],  (const float*)d_in[7],  (const float*)d_in[11]};
    const float* ASm[3] = {(const float*)d_in[4],  (const float*)d_in[8],  (const float*)d_in[12]};
    const float* ADm[3] = {(const float*)d_in[5],  (const float*)d_in[9],  (const float*)d_in[13]};
    const float* Bm[3]  = {(const float*)d_in[6],  (const float*)d_in[10], (const float*)d_in[14]};
    const float* P  = (const float*)d_in[15];
    const float* LW = (const float*)d_in[16];

    float* out = (float*)d_out;
    float* logits  = out;                                   // [64,2]
    float* probs   = out + GG * OUT_DIM;                    // [64,2]
    float* nodeEmb = out + 2 * GG * OUT_DIM;                // [N,100]
    float* GE      = nodeEmb + (size_t)NN * DENSE;          // [64,100]
    float* disto   = GE + GG * DENSE;                       // [64,10]

    // workspace carve-up
    char* w = (char*)d_ws;
    size_t off = 0;
    auto carve = [&](size_t bytes) -> void* {
        void* p = w + off;
        off += (bytes + 15) & ~(size_t)15;
        return p;
    };
    float* hA   = (float*)carve((size_t)NN * DENSE * 4);
    float* es   = (float*)carve((size_t)NN * HEADS * 4);
    float* ed   = (float*)carve((size_t)NN * HEADS * 4);
    int* cnt    = (int*)carve((size_t)NN * 4);
    int* offs   = (int*)carve((size_t)(NN + 1) * 4);
    int* pos    = (int*)carve((size_t)ETOT * 4);
    int* csr    = (int*)carve((size_t)ETOT * 4);
    int* csum   = (int*)carve((size_t)(NCHUNK + 1) * 4);
    int* gstart = (int*)carve((size_t)(GG + 1) * 4);
    float* part = (float*)carve((size_t)GG * 8 * DENSE * 4);
    float* wv   = (float*)carve((size_t)ETOT * HEADS * 4);   // per-edge weights
    (void)in_sizes; (void)n_in; (void)out_size; (void)ws_size;

    // ---- CSR build (once, reused for all 3 layers) ----
    hipMemsetAsync(cnt, 0, (size_t)NN * 4, stream);
    k_count<<<(ETOT + 255) / 256, 256, 0, stream>>>(ei, cnt, pos);
    k_scan1<<<NCHUNK, 256, 0, stream>>>(cnt, csum);
    k_scan2<<<1, 256, 0, stream>>>(csum);
    k_scan3<<<NCHUNK, 256, 0, stream>>>(cnt, csum, offs);
    k_scatter<<<(ETOT + 255) / 256, 256, 0, stream>>>(ei, offs, pos, csr);
    k_bounds<<<(NN + 255) / 256, 256, 0, stream>>>(batch, gstart);

    const int gemmGrid = (NN + 127) / 128;
    const int esedGrid = (NN * HEADS + 255) / 256;
    const int msumGrid = (NN + 3) / 4;
    const int accGrid  = (NN + 1) / 2;

    const float* layerIn = x;
    for (int l = 0; l < 3; ++l) {
        if (l == 0) k_gemm<IN_DIM, 32><<<gemmGrid, 256, 0, stream>>>(layerIn, Wm[l], hA);
        else        k_gemm<DENSE,  20><<<gemmGrid, 256, 0, stream>>>(layerIn, Wm[l], hA);
        k_esed<<<esedGrid, 256, 0, stream>>>(hA, ASm[l], ADm[l], es, ed);
        k_msum<<<msumGrid, 256, 0, stream>>>(es, ed, offs, csr, wv);
        k_acc<<<accGrid, 128, 0, stream>>>(hA, wv, offs, csr, Bm[l], nodeEmb);
        layerIn = nodeEmb;
    }

    // ---- pooling ----
    k_pool1<<<GG * 8, 128, 0, stream>>>(nodeEmb, gstart, part);
    k_pool2<<<GG, 128, 0, stream>>>(part, GE);

    // ---- prototype head ----
    k_head<<<GG, 128, 0, stream>>>(GE, P, LW, logits, probs, disto);
}